// Round 13
// baseline (558.143 us; speedup 1.0000x reference)
//
#include <hip/hip_runtime.h>
#include <hip/hip_bf16.h>

#define Hd 1024
#define Bdim 2
#define Sd 2048
#define BSd 4096
#define Vd 32000
#define EPSf 1e-5f
#define CH 16
#define NCH 128
#define NT3 448   // total packed state dim 64+128+256

typedef __attribute__((ext_vector_type(8))) short short8;
typedef __attribute__((ext_vector_type(4))) float f32x4;
typedef __attribute__((ext_vector_type(4))) unsigned short us4;

__device__ __forceinline__ unsigned short f2bf(float f) {
  union { float f; unsigned int u; } v; v.f = f;
  return (unsigned short)((v.u + 0x7fffu + ((v.u >> 16) & 1u)) >> 16);
}

typedef __attribute__((address_space(1))) const void gvoid_t;
typedef __attribute__((address_space(3))) void svoid_t;
__device__ __forceinline__ void gl_lds16(const void* g, void* s) {
  __builtin_amdgcn_global_load_lds((gvoid_t*)g, (svoid_t*)s, 16, 0, 0);
}

// ---------------- batched fp32 -> bf16 convert (11 jobs, 1 launch) ----------------
struct CvtTab {
  const float* src[11];
  unsigned short* dst[11];
  int start[12];
};
__global__ void k_cvt_all(CvtTab tab) {
  int b = blockIdx.x;
  int j = 0;
  while (j < 10 && b >= tab.start[j + 1]) ++j;
  size_t i = (size_t)(b - tab.start[j]) * 256 + threadIdx.x;
  f32x4 v = *(const f32x4*)(tab.src[j] + i * 4);
  us4 o;
  o[0] = f2bf(v[0]); o[1] = f2bf(v[1]); o[2] = f2bf(v[2]); o[3] = f2bf(v[3]);
  *(us4*)(tab.dst[j] + i * 4) = o;
}

// ---------------- transposing convert: dst[k][j] = bf16(src[j][k]), 1024x1024 x3 ----------------
__global__ void k_cvtT(const float* __restrict__ s0, const float* __restrict__ s1,
                       const float* __restrict__ s2, unsigned short* __restrict__ dst) {
  const float* src = blockIdx.z == 0 ? s0 : (blockIdx.z == 1 ? s1 : s2);
  unsigned short* d = dst + (size_t)blockIdx.z * Hd * Hd;
  __shared__ float tile[32][33];
  int tx = threadIdx.x & 31, ty = threadIdx.x >> 5;
  int bx = blockIdx.x * 32, by = blockIdx.y * 32;
  #pragma unroll
  for (int i = 0; i < 4; ++i)
    tile[ty + i * 8][tx] = src[(size_t)(by + ty + i * 8) * Hd + bx + tx];
  __syncthreads();
  #pragma unroll
  for (int i = 0; i < 4; ++i)
    d[(size_t)(bx + ty + i * 8) * Hd + by + tx] = f2bf(tile[tx][ty + i * 8]);
}

// ---------------- folded bias: biasf[h] = bf[h] + sum_c Wf[h][c]*bo_cat[c] ----------------
__global__ void k_biasf(const float* __restrict__ Wf_, const float* __restrict__ bfb,
                        const float* __restrict__ bo0, const float* __restrict__ bo1,
                        const float* __restrict__ bo2, float* __restrict__ biasf) {
  int h = blockIdx.x, t = threadIdx.x;
  float s = 0.f;
  for (int c = t; c < 3072; c += 256) {
    float b = c < 1024 ? bo0[c] : (c < 2048 ? bo1[c - 1024] : bo2[c - 2048]);
    s += Wf_[(size_t)h * 3072 + c] * b;
  }
  #pragma unroll
  for (int o = 32; o >= 1; o >>= 1) s += __shfl_xor(s, o);
  __shared__ float red[4];
  if ((t & 63) == 0) red[t >> 6] = s;
  __syncthreads();
  if (t == 0) biasf[h] = bfb[h] + red[0] + red[1] + red[2] + red[3];
}

// ---------------- pack per-layer small params ----------------
__global__ void k_setup(const float* A0, const float* A1, const float* A2,
                        const float* b0, const float* b1, const float* b2,
                        const float* D0, const float* D1, const float* D2,
                        const float* g0, const float* g1, const float* g2,
                        const float* e0, const float* e1, const float* e2,
                        float* Alog448, float* bg448,
                        float* D3, float* g3, float* be3) {
  int t = blockIdx.x * 256 + threadIdx.x;
  if (t < NT3) {
    int l = t < 64 ? 0 : (t < 192 ? 1 : 2);
    int o = t - (l == 0 ? 0 : (l == 1 ? 64 : 192));
    Alog448[t] = (l == 0 ? A0 : (l == 1 ? A1 : A2))[o];
    bg448[t]   = (l == 0 ? b0 : (l == 1 ? b1 : b2))[o];
  }
  if (t < 3072) {
    int l = t >> 10, o = t & 1023;
    D3[t]  = (l == 0 ? D0 : (l == 1 ? D1 : D2))[o];
    g3[t]  = (l == 0 ? g0 : (l == 1 ? g1 : g2))[o];
    be3[t] = (l == 0 ? e0 : (l == 1 ? e1 : e2))[o];
  }
}

// ---------------- embedding gather -> fp32 + bf16 ----------------
__global__ void k_embed(const int* __restrict__ x, const float* __restrict__ E,
                        float* __restrict__ emb, unsigned short* __restrict__ embbf) {
  int row = blockIdx.x, t = threadIdx.x;
  int id = x[row];
  f32x4 v = *(const f32x4*)(E + (size_t)id * Hd + t * 4);
  *(f32x4*)(emb + (size_t)row * Hd + t * 4) = v;
  us4 o;
  o[0] = f2bf(v[0]); o[1] = f2bf(v[1]); o[2] = f2bf(v[2]); o[3] = f2bf(v[3]);
  *(us4*)(embbf + (size_t)row * Hd + t * 4) = o;
}

// ---------------- bf16 NT GEMM, 2-phase double-buffered (proven r4) ----------------
template<int BM, int BN, int WM, int WN, int BF16_OUT>
__launch_bounds__(WM * WN * 64)
__global__ void gemm2ph(const unsigned short* __restrict__ A,
                        const unsigned short* __restrict__ Bw,
                        const float* __restrict__ bias,
                        void* __restrict__ Cv,
                        int N, int K, int lda, int ldb, int ldc, int coff, int tm)
{
  constexpr int NT = WM * WN * 64;
  constexpr int MF = BM / WM / 16;
  constexpr int NF = BN / WN / 16;
  constexpr int ASZ = BM * 64;
  constexpr int BSZ = BN * 64;
  constexpr int AR = (ASZ * 2) / (NT * 16);
  constexpr int BR = (BSZ * 2) / (NT * 16);
  __shared__ __align__(16) unsigned short Sm[2 * (ASZ + BSZ)];

  int T = gridDim.x;
  int orig = blockIdx.x;
  int q = T >> 3, r = T & 7;
  int xc = orig & 7, sdv = orig >> 3;
  int wgid = (xc < r ? xc * (q + 1) : r * (q + 1) + (xc - r) * q) + sdv;
  int n_t = wgid / tm, m_t = wgid % tm;
  int row0 = m_t * BM, col0 = n_t * BN;

  int tid = threadIdx.x;
  int wave = tid >> 6, lane = tid & 63;
  int wm = wave / WN, wn = wave % WN;
  int wr = wm * (BM / WM), wc = wn * (BN / WN);
  int lr = lane & 15;
  int klane = lane >> 4;

  f32x4 acc[MF][NF] = {};

  auto stage = [&](int buf, int k0) {
    unsigned short* Ab = Sm + buf * (ASZ + BSZ);
    unsigned short* Bb = Ab + ASZ;
    #pragma unroll
    for (int j = 0; j < AR; ++j) {
      int slot = j * NT + tid;
      int lrow = slot >> 3, c16 = slot & 7;
      int scol = (c16 ^ (lrow & 7)) * 8;
      gl_lds16(A + (size_t)(row0 + lrow) * lda + k0 + scol, Ab + (j * NT + wave * 64) * 8);
    }
    #pragma unroll
    for (int j = 0; j < BR; ++j) {
      int slot = j * NT + tid;
      int lrow = slot >> 3, c16 = slot & 7;
      int scol = (c16 ^ (lrow & 7)) * 8;
      int brow = col0 + lrow;
      if (brow >= N) brow = N - 1;
      gl_lds16(Bw + (size_t)brow * ldb + k0 + scol, Bb + (j * NT + wave * 64) * 8);
    }
  };

  auto compute = [&](int buf) {
    const unsigned short* Ab = Sm + buf * (ASZ + BSZ);
    const unsigned short* Bb = Ab + ASZ;
    #pragma unroll
    for (int kk = 0; kk < 2; ++kk) {
      short8 afr[MF], bfr[NF];
      #pragma unroll
      for (int m = 0; m < MF; ++m) {
        int row = wr + m * 16 + lr;
        int cs = (kk * 4 + klane) ^ (row & 7);
        afr[m] = *(const short8*)(Ab + row * 64 + cs * 8);
      }
      #pragma unroll
      for (int n = 0; n < NF; ++n) {
        int row = wc + n * 16 + lr;
        int cs = (kk * 4 + klane) ^ (row & 7);
        bfr[n] = *(const short8*)(Bb + row * 64 + cs * 8);
      }
      #pragma unroll
      for (int m = 0; m < MF; ++m)
        #pragma unroll
        for (int n = 0; n < NF; ++n)
          acc[m][n] = __builtin_amdgcn_mfma_f32_16x16x32_bf16(afr[m], bfr[n], acc[m][n], 0, 0, 0);
    }
  };

  int nt = K >> 6;
  stage(0, 0);
  __syncthreads();
  for (int t = 0; t < nt - 1; ++t) {
    stage((t & 1) ^ 1, (t + 1) * 64);
    compute(t & 1);
    __syncthreads();
  }
  compute((nt - 1) & 1);

  int rb = (lane >> 4) * 4;
  #pragma unroll
  for (int m = 0; m < MF; ++m) {
    #pragma unroll
    for (int n = 0; n < NF; ++n) {
      int gcol = col0 + wc + n * 16 + lr;
      if (gcol >= N) continue;
      float bv = bias ? bias[gcol] : 0.f;
      #pragma unroll
      for (int j = 0; j < 4; ++j) {
        int grow = row0 + wr + m * 16 + rb + j;
        float val = acc[m][n][j] + bv;
        if (BF16_OUT)
          ((unsigned short*)Cv)[(size_t)grow * ldc + coff + gcol] = f2bf(val);
        else
          ((float*)Cv)[(size_t)grow * ldc + coff + gcol] = val;
      }
    }
  }
}

// ---------------- batched 3-layer Wc GEMM (768 blocks, one launch) ----------------
__launch_bounds__(256)
__global__ void gemm_wc3(const unsigned short* __restrict__ St,
                         const unsigned short* __restrict__ Wc,
                         float* __restrict__ Cv)
{
  constexpr int ASZ = 128 * 64, BSZ = 128 * 64;
  __shared__ __align__(16) unsigned short Sm[2 * (ASZ + BSZ)];
  int T = gridDim.x;
  int orig = blockIdx.x;
  int q = T >> 3, r = T & 7;
  int xc = orig & 7, sdv = orig >> 3;
  int wgid = (xc < r ? xc * (q + 1) : r * (q + 1) + (xc - r) * q) + sdv;
  int l = wgid % 3;
  int w2 = wgid / 3;
  int n_t = w2 >> 5, m_t = w2 & 31;
  const int owgl = l == 0 ? 0 : (l == 1 ? 64 : 192);
  const int K = 64 << l;
  const unsigned short* A = St + owgl;
  const unsigned short* Bw = Wc + (size_t)owgl * Hd;
  int row0 = m_t * 128, col0 = n_t * 128;

  int tid = threadIdx.x;
  int wave = tid >> 6, lane = tid & 63;
  int wm = wave >> 1, wn = wave & 1;
  int wr = wm * 64, wc = wn * 64;
  int lr = lane & 15, klane = lane >> 4;

  f32x4 acc[4][4] = {};
  auto stage = [&](int buf, int k0) {
    unsigned short* Ab = Sm + buf * (ASZ + BSZ);
    unsigned short* Bb = Ab + ASZ;
    #pragma unroll
    for (int j = 0; j < 4; ++j) {
      int slot = j * 256 + tid;
      int lrow = slot >> 3, c16 = slot & 7;
      int scol = (c16 ^ (lrow & 7)) * 8;
      gl_lds16(A + (size_t)(row0 + lrow) * NT3 + k0 + scol, Ab + (j * 256 + wave * 64) * 8);
      gl_lds16(Bw + (size_t)(col0 + lrow) * K + k0 + scol, Bb + (j * 256 + wave * 64) * 8);
    }
  };
  auto compute = [&](int buf) {
    const unsigned short* Ab = Sm + buf * (ASZ + BSZ);
    const unsigned short* Bb = Ab + ASZ;
    #pragma unroll
    for (int kk = 0; kk < 2; ++kk) {
      short8 afr[4], bfr[4];
      #pragma unroll
      for (int m = 0; m < 4; ++m) {
        int row = wr + m * 16 + lr;
        int cs = (kk * 4 + klane) ^ (row & 7);
        afr[m] = *(const short8*)(Ab + row * 64 + cs * 8);
      }
      #pragma unroll
      for (int n = 0; n < 4; ++n) {
        int row = wc + n * 16 + lr;
        int cs = (kk * 4 + klane) ^ (row & 7);
        bfr[n] = *(const short8*)(Bb + row * 64 + cs * 8);
      }
      #pragma unroll
      for (int m = 0; m < 4; ++m)
        #pragma unroll
        for (int n = 0; n < 4; ++n)
          acc[m][n] = __builtin_amdgcn_mfma_f32_16x16x32_bf16(afr[m], bfr[n], acc[m][n], 0, 0, 0);
    }
  };
  int nt = K >> 6;
  stage(0, 0);
  __syncthreads();
  for (int t = 0; t < nt - 1; ++t) {
    stage((t & 1) ^ 1, (t + 1) * 64);
    compute(t & 1);
    __syncthreads();
  }
  compute((nt - 1) & 1);

  int rb = (lane >> 4) * 4;
  #pragma unroll
  for (int m = 0; m < 4; ++m)
    #pragma unroll
    for (int n = 0; n < 4; ++n) {
      int gcol = l * Hd + col0 + wc + n * 16 + lr;
      #pragma unroll
      for (int j = 0; j < 4; ++j) {
        int grow = row0 + wr + m * 16 + rb + j;
        Cv[(size_t)grow * 3072 + gcol] = acc[m][n][j];
      }
    }
}

// ---------------- block-diagonal composed-weight GEMM (one launch, 3 layers) ----------------
__launch_bounds__(256)
__global__ void gemm_bd3(const unsigned short* __restrict__ Awf,
                         const unsigned short* __restrict__ Bwo,
                         unsigned short* __restrict__ Cw)
{
  constexpr int ASZ = 128 * 64, BSZ = 128 * 64;
  __shared__ __align__(16) unsigned short Sm[2 * (ASZ + BSZ)];
  int T = gridDim.x;
  int orig = blockIdx.x;
  int q = T >> 3, r = T & 7;
  int xc = orig & 7, sdv = orig >> 3;
  int wgid = (xc < r ? xc * (q + 1) : r * (q + 1) + (xc - r) * q) + sdv;
  int n_g = wgid / 8, m_t = wgid % 8;
  int li = n_g >> 3, n_t = n_g & 7;
  const unsigned short* A = Awf + li * Hd;
  const unsigned short* Bw = Bwo + ((size_t)li << 20);
  int row0 = m_t * 128, col0 = n_t * 128;

  int tid = threadIdx.x;
  int wave = tid >> 6, lane = tid & 63;
  int wm = wave >> 1, wn = wave & 1;
  int wr = wm * 64, wc = wn * 64;
  int lr = lane & 15, klane = lane >> 4;

  f32x4 acc[4][4] = {};
  auto stage = [&](int buf, int k0) {
    unsigned short* Ab = Sm + buf * (ASZ + BSZ);
    unsigned short* Bb = Ab + ASZ;
    #pragma unroll
    for (int j = 0; j < 4; ++j) {
      int slot = j * 256 + tid;
      int lrow = slot >> 3, c16 = slot & 7;
      int scol = (c16 ^ (lrow & 7)) * 8;
      gl_lds16(A + (size_t)(row0 + lrow) * 3072 + k0 + scol, Ab + (j * 256 + wave * 64) * 8);
      gl_lds16(Bw + (size_t)(col0 + lrow) * 1024 + k0 + scol, Bb + (j * 256 + wave * 64) * 8);
    }
  };
  auto compute = [&](int buf) {
    const unsigned short* Ab = Sm + buf * (ASZ + BSZ);
    const unsigned short* Bb = Ab + ASZ;
    #pragma unroll
    for (int kk = 0; kk < 2; ++kk) {
      short8 afr[4], bfr[4];
      #pragma unroll
      for (int m = 0; m < 4; ++m) {
        int row = wr + m * 16 + lr;
        int cs = (kk * 4 + klane) ^ (row & 7);
        afr[m] = *(const short8*)(Ab + row * 64 + cs * 8);
      }
      #pragma unroll
      for (int n = 0; n < 4; ++n) {
        int row = wc + n * 16 + lr;
        int cs = (kk * 4 + klane) ^ (row & 7);
        bfr[n] = *(const short8*)(Bb + row * 64 + cs * 8);
      }
      #pragma unroll
      for (int m = 0; m < 4; ++m)
        #pragma unroll
        for (int n = 0; n < 4; ++n)
          acc[m][n] = __builtin_amdgcn_mfma_f32_16x16x32_bf16(afr[m], bfr[n], acc[m][n], 0, 0, 0);
    }
  };
  stage(0, 0);
  __syncthreads();
  for (int t = 0; t < 15; ++t) {
    stage((t & 1) ^ 1, (t + 1) * 64);
    compute(t & 1);
    __syncthreads();
  }
  compute(1);

  int rb = (lane >> 4) * 4;
  #pragma unroll
  for (int m = 0; m < 4; ++m)
    #pragma unroll
    for (int n = 0; n < 4; ++n) {
      int gcol = li * Hd + col0 + wc + n * 16 + lr;
      #pragma unroll
      for (int j = 0; j < 4; ++j) {
        int grow = row0 + wr + m * 16 + rb + j;
        Cw[(size_t)grow * 3072 + gcol] = f2bf(acc[m][n][j]);
      }
    }
}

// ---------------- 8-phase 256x256 NT GEMM (logits) — template-conformant ----------------
// r13 change: stage issues moved PRE-barrier (m201 template order:
// ds_reads -> stage -> barrier -> MFMA -> barrier). Safety: passing phase-p's
// closing barrier proves all waves' phase-p ds_reads COMPLETED (lgkmcnt(0)
// precedes MFMA, MFMA precedes barrier); each stage targets a region whose
// last-reader phase closed >=1 barrier earlier in program order.
// vmcnt(4) at ph4/ph8 unchanged (FIFO: waits cover all older stages).
// Supertile dispatch (16m x 16n per 256-block group) retained.
__launch_bounds__(512)
__global__ void gemm8ph(const unsigned short* __restrict__ A,
                        const unsigned short* __restrict__ Bw,
                        const float* __restrict__ bias,
                        float* __restrict__ Cv,
                        int N, int K, int lda, int ldb, int ldc, int tn)
{
  __shared__ __align__(16) unsigned short Sm[65536];  // A: 4x8192, B: 4x8192 (128 KB)

  int wgid = blockIdx.x;
  int grp = wgid >> 8;
  int rem = wgid & 255;
  int n_t = grp * 16 + (rem >> 4);
  int m_t = rem & 15;
  int row0 = m_t * 256, col0 = n_t * 256;

  int tid = threadIdx.x;
  int wave = tid >> 6, lane = tid & 63;
  int wm = wave >> 2, wn = wave & 3;   // 2M x 4N
  int lr = lane & 15, klane = lane >> 4;

  f32x4 acc[8][4] = {};

  auto stageA = [&](int b, int h, int kt) {
    unsigned short* base = Sm + (b * 2 + h) * 8192;
    #pragma unroll
    for (int j = 0; j < 2; ++j) {
      int slot = j * 512 + tid;
      int lrow = slot >> 3, c16 = slot & 7;
      int scol = (c16 ^ (lrow & 7)) * 8;
      gl_lds16(A + (size_t)(row0 + h * 128 + lrow) * lda + kt * 64 + scol,
               base + (j * 512 + wave * 64) * 8);
    }
  };
  auto stageB = [&](int b, int h, int kt) {
    unsigned short* base = Sm + 32768 + (b * 2 + h) * 8192;
    #pragma unroll
    for (int j = 0; j < 2; ++j) {
      int slot = j * 512 + tid;
      int lrow = slot >> 3, c16 = slot & 7;
      int scol = (c16 ^ (lrow & 7)) * 8;
      gl_lds16(Bw + (size_t)(col0 + h * 128 + lrow) * ldb + kt * 64 + scol,
               base + (j * 512 + wave * 64) * 8);
    }
  };
  auto readA = [&](short8* afr, int b, int mh, int kk) {
    const unsigned short* base = Sm + (b * 2 + mh) * 8192;
    #pragma unroll
    for (int f = 0; f < 4; ++f) {
      int rowin = f * 32 + wm * 16 + lr;
      int cs = (kk * 4 + klane) ^ (rowin & 7);
      afr[f] = *(const short8*)(base + rowin * 64 + cs * 8);
    }
  };
  auto readB = [&](short8* bfr, int b, int kk) {
    #pragma unroll
    for (int n = 0; n < 4; ++n) {
      int rowin = (n & 1) * 64 + wn * 16 + lr;
      const unsigned short* base = Sm + 32768 + (b * 2 + (n >> 1)) * 8192;
      int cs = (kk * 4 + klane) ^ (rowin & 7);
      bfr[n] = *(const short8*)(base + rowin * 64 + cs * 8);
    }
  };

  #define MFMA16(mh, afr, bfr)                                                  \
    __builtin_amdgcn_s_setprio(1);                                              \
    _Pragma("unroll")                                                           \
    for (int f = 0; f < 4; ++f)                                                 \
      _Pragma("unroll")                                                         \
      for (int n = 0; n < 4; ++n)                                               \
        acc[(mh) * 4 + f][n] = __builtin_amdgcn_mfma_f32_16x16x32_bf16(         \
            afr[f], bfr[n], acc[(mh) * 4 + f][n], 0, 0, 0);                     \
    __builtin_amdgcn_s_setprio(0);

  #define BAR()   __builtin_amdgcn_s_barrier()
  #define VM4()   asm volatile("s_waitcnt vmcnt(4)" ::: "memory")
  #define VM0()   asm volatile("s_waitcnt vmcnt(0)" ::: "memory")

  int nt = K >> 6;          // 16
  int iters = K >> 7;       // 8

  // prologue: T0 all 4 halves + T1.Ah0, T1.Bh0
  stageA(0, 0, 0); stageB(0, 0, 0); stageB(0, 1, 0); stageA(0, 1, 0);
  stageA(1, 0, 1); stageB(1, 0, 1);
  VM4(); BAR();

  short8 afr[4], bfr0[4], bfr1[4];
  for (int i = 0; i < iters; ++i) {
    int t1 = 2 * i + 1, t2 = 2 * i + 2, t3 = 2 * i + 3;
    bool last = (i == iters - 1);
    // ph1: reads buf0 | stage buf1.Bh1,Ah1 <- T1 (pre-barrier)
    readA(afr, 0, 0, 0); readB(bfr0, 0, 0);
    stageB(1, 1, t1); stageA(1, 1, t1);
    BAR();
    MFMA16(0, afr, bfr0);
    BAR();
    // ph2
    readA(afr, 0, 0, 1); readB(bfr1, 0, 1);
    BAR();
    MFMA16(0, afr, bfr1);
    BAR();
    // ph3: stage buf0.Ah0 <- T2 (pre-barrier; Ah0 last read ph2, barrier-closed)
    readA(afr, 0, 1, 0);
    if (t2 < nt) stageA(0, 0, t2);
    BAR();
    MFMA16(1, afr, bfr0);
    BAR();
    // ph4: stage buf0.Bh0 <- T2 | vmcnt
    readA(afr, 0, 1, 1);
    if (t2 < nt) stageB(0, 0, t2);
    BAR();
    MFMA16(1, afr, bfr1);
    if (last) { VM0(); } else { VM4(); }
    BAR();
    // ph5: reads buf1 | stage buf0.Bh1,Ah1 <- T2
    readA(afr, 1, 0, 0); readB(bfr0, 1, 0);
    if (t2 < nt) { stageB(0, 1, t2); stageA(0, 1, t2); }
    BAR();
    MFMA16(0, afr, bfr0);
    BAR();
    // ph6
    readA(afr, 1, 0, 1); readB(bfr1, 1, 1);
    BAR();
    MFMA16(0, afr, bfr1);
    BAR();
    // ph7: stage buf1.Ah0 <- T3
    readA(afr, 1, 1, 0);
    if (t3 < nt) stageA(1, 0, t3);
    BAR();
    MFMA16(1, afr, bfr0);
    BAR();
    // ph8: stage buf1.Bh0 <- T3 | vmcnt
    readA(afr, 1, 1, 1);
    if (t3 < nt) stageB(1, 0, t3);
    BAR();
    MFMA16(1, afr, bfr1);
    if (!last) { VM4(); }
    BAR();
  }

  int rb = (lane >> 4) * 4;
  #pragma unroll
  for (int idx = 0; idx < 8; ++idx) {
    int mh = idx >> 2, f = idx & 3;
    int growb = row0 + mh * 128 + f * 32 + wm * 16 + rb;
    #pragma unroll
    for (int n = 0; n < 4; ++n) {
      int gcol = col0 + (n & 1) * 64 + (n >> 1) * 128 + wn * 16 + lr;
      float bv = bias[gcol];
      #pragma unroll
      for (int j = 0; j < 4; ++j)
        Cv[(size_t)(growb + j) * ldc + gcol] = acc[idx][n][j] + bv;
    }
  }
  #undef MFMA16
  #undef BAR
  #undef VM4
  #undef VM0
}

// ---------------- packed 3-layer chunked diagonal scan ----------------
__global__ void k_scanA(const float* __restrict__ gzbx, const float* __restrict__ Alog448,
                        const float* __restrict__ bg448,
                        float* __restrict__ st, float* __restrict__ carry) {
  int gid = blockIdx.x * 256 + threadIdx.x;
  if (gid >= Bdim * NCH * NT3) return;
  int n = gid % NT3;
  int c = (gid / NT3) % NCH;
  int b = gid / (NT3 * NCH);
  float a = expf(Alog448[n]);
  float bgv = bg448[n];
  float s = 0.f;
  size_t rbase = (size_t)b * Sd + (size_t)c * CH;
  for (int t = 0; t < CH; ++t) {
    size_t row = rbase + t;
    float gzv = gzbx[row * 896 + n];
    float bxv = gzbx[row * 896 + 448 + n];
    float gv = 1.f / (1.f + expf(-(gzv + bgv)));
    s = a * s + gv * bxv;
    st[row * NT3 + n] = s;
  }
  carry[((size_t)b * NCH + c) * NT3 + n] = s;
}

__global__ void k_scanB(const float* __restrict__ carry, const float* __restrict__ Alog448,
                        float* __restrict__ cin) {
  int i = blockIdx.x * 256 + threadIdx.x;
  if (i >= Bdim * NT3) return;
  int b = i / NT3, n = i % NT3;
  float aC = expf((float)CH * Alog448[n]);
  float s = 0.f;
  for (int c = 0; c < NCH; ++c) {
    cin[((size_t)b * NCH + c) * NT3 + n] = s;
    s = aC * s + carry[((size_t)b * NCH + c) * NT3 + n];
  }
}

__global__ void k_scanC(const float* __restrict__ st, const float* __restrict__ cin,
                        const float* __restrict__ Alog448, unsigned short* __restrict__ stbf) {
  size_t gid = (size_t)blockIdx.x * 256 + threadIdx.x;
  if (gid >= (size_t)BSd * NT3) return;
  int n = gid % NT3;
  int row = gid / NT3;
  int b = row / Sd, sg = row % Sd;
  int c = sg / CH, t = sg % CH;
  float cv = cin[((size_t)b * NCH + c) * NT3 + n];
  float val = st[gid] + expf((float)(t + 1) * Alog448[n]) * cv;
  stbf[gid] = f2bf(val);
}

// ---------------- 3-layer fused LN ----------------
__global__ void k_ln3(const float* __restrict__ y3, const float* __restrict__ emb,
                      const float* __restrict__ D3, const float* __restrict__ g3,
                      const float* __restrict__ be3, unsigned short* __restrict__ z3) {
  int row = blockIdx.x, ly = blockIdx.y, t = threadIdx.x;
  const float* y = y3 + (size_t)row * 3072 + ly * 1024;
  f32x4 yv = *(const f32x4*)(y + t * 4);
  f32x4 ev = *(const f32x4*)(emb + (size_t)row * Hd + t * 4);
  float vals[4];
  float sum = 0.f, sq = 0.f;
  #pragma unroll
  for (int j = 0; j < 4; ++j) {
    float coef = D3[ly * 1024 + t * 4 + j] + 1.f;
    float v = yv[j] + coef * ev[j];
    vals[j] = v; sum += v; sq += v * v;
  }
  #pragma unroll
  for (int o = 32; o >= 1; o >>= 1) {
    sum += __shfl_xor(sum, o);
    sq += __shfl_xor(sq, o);
  }
  __shared__ float red[2][4];
  int w = t >> 6, lane = t & 63;
  if (lane == 0) { red[0][w] = sum; red[1][w] = sq; }
  __syncthreads();
  sum = red[0][0] + red[0][1] + red[0][2] + red[0][3];
  sq  = red[1][0] + red[1][1] + red[1][2] + red[1][3];
  float mean = sum * (1.f / Hd);
  float var = sq * (1.f / Hd) - mean * mean;
  float rs = rsqrtf(var + EPSf);
  us4 o4;
  #pragma unroll
  for (int j = 0; j < 4; ++j) {
    float z = (vals[j] - mean) * rs * g3[ly * 1024 + t * 4 + j] + be3[ly * 1024 + t * 4 + j];
    o4[j] = f2bf(z);
  }
  *(us4*)(z3 + (size_t)row * 3072 + ly * 1024 + t * 4) = o4;
}

// ---------------- final LN (coef 1) ----------------
__global__ void k_ln(const float* __restrict__ y, const float* __restrict__ emb,
                     const float* __restrict__ g, const float* __restrict__ be,
                     unsigned short* __restrict__ out) {
  int row = blockIdx.x, t = threadIdx.x;
  f32x4 yv = *(const f32x4*)(y + (size_t)row * Hd + t * 4);
  f32x4 ev = *(const f32x4*)(emb + (size_t)row * Hd + t * 4);
  float vals[4];
  float sum = 0.f, sq = 0.f;
  #pragma unroll
  for (int j = 0; j < 4; ++j) {
    float v = yv[j] + ev[j];
    vals[j] = v; sum += v; sq += v * v;
  }
  #pragma unroll
  for (int o = 32; o >= 1; o >>= 1) {
    sum += __shfl_xor(sum, o);
    sq += __shfl_xor(sq, o);
  }
  __shared__ float red[2][4];
  int w = t >> 6, lane = t & 63;
  if (lane == 0) { red[0][w] = sum; red[1][w] = sq; }
  __syncthreads();
  sum = red[0][0] + red[0][1] + red[0][2] + red[0][3];
  sq  = red[1][0] + red[1][1] + red[1][2] + red[1][3];
  float mean = sum * (1.f / Hd);
  float var = sq * (1.f / Hd) - mean * mean;
  float rs = rsqrtf(var + EPSf);
  us4 o4;
  #pragma unroll
  for (int j = 0; j < 4; ++j) {
    float z = (vals[j] - mean) * rs * g[t * 4 + j] + be[t * 4 + j];
    o4[j] = f2bf(z);
  }
  *(us4*)(out + (size_t)row * Hd + t * 4) = o4;
}

extern "C" void kernel_launch(void* const* d_in, const int* in_sizes, int n_in,
                              void* d_out, int out_size, void* d_ws, size_t ws_size,
                              hipStream_t stream) {
  (void)in_sizes; (void)n_in; (void)out_size; (void)ws_size;
  const int* x = (const int*)d_in[0];
  const float* E = (const float*)d_in[1];
  const float* Wf_ = (const float*)d_in[32];
  const float* bfb = (const float*)d_in[33];
  const float* gfp = (const float*)d_in[34];
  const float* bef = (const float*)d_in[35];
  const float* Wh_ = (const float*)d_in[36];
  const float* bh = (const float*)d_in[37];

  char* wsb = (char*)d_ws;
  size_t off = 0;
  auto alloc = [&](size_t bytes) -> void* {
    void* p = wsb + off;
    off += (bytes + 255) & ~(size_t)255;
    return p;
  };
  float* emb             = (float*)alloc((size_t)BSd * Hd * 4);
  unsigned short* embbf  = (unsigned short*)alloc((size_t)BSd * Hd * 2);
  unsigned short* wgwbbf = (unsigned short*)alloc((size_t)896 * Hd * 2);
  unsigned short* wcbf   = (unsigned short*)alloc((size_t)NT3 * Hd * 2);
  unsigned short* wotbf  = (unsigned short*)alloc((size_t)3 * Hd * Hd * 2);
  unsigned short* wfbf   = (unsigned short*)alloc((size_t)3 * Hd * Hd * 2);
  unsigned short* wcombbf= (unsigned short*)alloc((size_t)Hd * 3 * Hd * 2);
  unsigned short* whbf   = (unsigned short*)alloc((size_t)Vd * Hd * 2);
  float* gzbx            = (float*)alloc((size_t)BSd * 896 * 4);
  float* stl             = (float*)alloc((size_t)BSd * NT3 * 4);
  unsigned short* stbf   = (unsigned short*)alloc((size_t)BSd * NT3 * 2);
  float* carry           = (float*)alloc((size_t)Bdim * NCH * NT3 * 4);
  float* cin             = (float*)alloc((size_t)Bdim * NCH * NT3 * 4);
  float* ybuf3           = (float*)alloc((size_t)BSd * 3072 * 4);
  unsigned short* zbf3   = (unsigned short*)alloc((size_t)BSd * 3072 * 2);
  unsigned short* zbf    = (unsigned short*)alloc((size_t)BSd * Hd * 2);
  float* Alog448         = (float*)alloc(NT3 * 4);
  float* bg448           = (float*)alloc(NT3 * 4);
  float* D3              = (float*)alloc(3072 * 4);
  float* g3              = (float*)alloc(3072 * 4);
  float* be3             = (float*)alloc(3072 * 4);
  float* biasf           = (float*)alloc(Hd * 4);

  k_embed<<<BSd, 256, 0, stream>>>(x, E, emb, embbf);

  // batched weight conversion (Wg, Wb, Wc, Wf, Wh)
  {
    CvtTab tab;
    const int rowoff_g[3] = {0, 64, 192};
    int j = 0;
    int n4s[11];
    for (int i = 0; i < 3; ++i) { tab.src[j] = (const float*)d_in[2 + 10 * i + 4]; tab.dst[j] = wgwbbf + (size_t)rowoff_g[i] * Hd;         n4s[j] = (64 << i) * Hd / 4; ++j; }
    for (int i = 0; i < 3; ++i) { tab.src[j] = (const float*)d_in[2 + 10 * i + 1]; tab.dst[j] = wgwbbf + (size_t)(448 + rowoff_g[i]) * Hd;  n4s[j] = (64 << i) * Hd / 4; ++j; }
    for (int i = 0; i < 3; ++i) { tab.src[j] = (const float*)d_in[2 + 10 * i + 2]; tab.dst[j] = wcbf + (size_t)rowoff_g[i] * Hd;            n4s[j] = (64 << i) * Hd / 4; ++j; }
    tab.src[j] = Wf_; tab.dst[j] = wfbf; n4s[j] = 3 * Hd * Hd / 4; ++j;
    tab.src[j] = Wh_; tab.dst[j] = whbf; n4s[j] = Vd * Hd / 4; ++j;
    tab.start[0] = 0;
    for (int k = 0; k < 11; ++k) tab.start[k + 1] = tab.start[k] + (n4s[k] + 255) / 256;
    k_cvt_all<<<tab.start[11], 256, 0, stream>>>(tab);
  }

  // Wo transposed-convert (for composed-weight GEMMs)
  k_cvtT<<<dim3(32, 32, 3), 256, 0, stream>>>(
      (const float*)d_in[8], (const float*)d_in[18], (const float*)d_in[28], wotbf);

  k_setup<<<12, 256, 0, stream>>>(
      (const float*)d_in[2], (const float*)d_in[12], (const float*)d_in[22],
      (const float*)d_in[7], (const float*)d_in[17], (const float*)d_in[27],
      (const float*)d_in[5], (const float*)d_in[15], (const float*)d_in[25],
      (const float*)d_in[10], (const float*)d_in[20], (const float*)d_in[30],
      (const float*)d_in[11], (const float*)d_in[21], (const float*)d_in[31],
      Alog448, bg448, D3, g3, be3);

  k_biasf<<<Hd, 256, 0, stream>>>(Wf_, bfb,
      (const float*)d_in[9], (const float*)d_in[19], (const float*)d_in[29], biasf);

  // composed weights in ONE block-diagonal launch (192 blocks)
  gemm_bd3<<<192, 256, 0, stream>>>(wfbf, wotbf, wcombbf);

  const int TM = BSd / 128;  // 32

  // merged gate+Bx GEMM: [BSd,1024] x [896,1024]^T -> gzbx [BSd,896]
  gemm2ph<128,128,2,2,0><<<(896 / 128) * TM, 256, 0, stream>>>(
      embbf, wgwbbf, nullptr, gzbx, 896, Hd, Hd, Hd, 896, 0, TM);

  // packed 3-layer scan
  {
    int totA = Bdim * NCH * NT3;
    k_scanA<<<(totA + 255) / 256, 256, 0, stream>>>(gzbx, Alog448, bg448, stl, carry);
    k_scanB<<<(Bdim * NT3 + 255) / 256, 256, 0, stream>>>(carry, Alog448, cin);
    size_t totC = (size_t)BSd * NT3;
    k_scanC<<<(int)((totC + 255) / 256), 256, 0, stream>>>(stl, cin, Alog448, stbf);
  }

  // all 3 Wc GEMMs in ONE launch (768 blocks, layer interleaved)
  gemm_wc3<<<768, 256, 0, stream>>>(stbf, wcbf, ybuf3);

  // one 3-layer LN
  k_ln3<<<dim3(BSd, 3), 256, 0, stream>>>(ybuf3, emb, D3, g3, be3, zbf3);

  // fused = z3 @ Wcomb^T + biasf  (replaces 3 Wo GEMMs + Wf GEMM)
  gemm2ph<128,128,2,2,0><<<(Hd / 128) * TM, 256, 0, stream>>>(
      zbf3, wcombbf, biasf, ybuf3, Hd, 3 * Hd, 3 * Hd, 3 * Hd, Hd, 0, TM);
  k_ln<<<BSd, 256, 0, stream>>>(ybuf3, emb, gfp, bef, zbf);

  // logits: 8-phase 256x256, supertile dispatch, template-conformant stages
  const int TN = Vd / 256;  // 125
  gemm8ph<<<(BSd / 256) * TN, 512, 0, stream>>>(
      zbf, whbf, bh, (float*)d_out, Vd, Hd, Hd, Hd, Vd, TN);
}

// Round 14
// 548.238 us; speedup vs baseline: 1.0181x; 1.0181x over previous
//
#include <hip/hip_runtime.h>
#include <hip/hip_bf16.h>

#define Hd 1024
#define Bdim 2
#define Sd 2048
#define BSd 4096
#define Vd 32000
#define EPSf 1e-5f
#define CH 16
#define NCH 128
#define NT3 448   // total packed state dim 64+128+256

typedef __attribute__((ext_vector_type(8))) short short8;
typedef __attribute__((ext_vector_type(4))) float f32x4;
typedef __attribute__((ext_vector_type(4))) unsigned short us4;

__device__ __forceinline__ unsigned short f2bf(float f) {
  union { float f; unsigned int u; } v; v.f = f;
  return (unsigned short)((v.u + 0x7fffu + ((v.u >> 16) & 1u)) >> 16);
}

typedef __attribute__((address_space(1))) const void gvoid_t;
typedef __attribute__((address_space(3))) void svoid_t;
__device__ __forceinline__ void gl_lds16(const void* g, void* s) {
  __builtin_amdgcn_global_load_lds((gvoid_t*)g, (svoid_t*)s, 16, 0, 0);
}

// ---------------- batched fp32 -> bf16 convert (11 jobs, 1 launch) ----------------
struct CvtTab {
  const float* src[11];
  unsigned short* dst[11];
  int start[12];
};
__global__ void k_cvt_all(CvtTab tab) {
  int b = blockIdx.x;
  int j = 0;
  while (j < 10 && b >= tab.start[j + 1]) ++j;
  size_t i = (size_t)(b - tab.start[j]) * 256 + threadIdx.x;
  f32x4 v = *(const f32x4*)(tab.src[j] + i * 4);
  us4 o;
  o[0] = f2bf(v[0]); o[1] = f2bf(v[1]); o[2] = f2bf(v[2]); o[3] = f2bf(v[3]);
  *(us4*)(tab.dst[j] + i * 4) = o;
}

// ---------------- transposing convert: dst[k][j] = bf16(src[j][k]), 1024x1024 x3 ----------------
__global__ void k_cvtT(const float* __restrict__ s0, const float* __restrict__ s1,
                       const float* __restrict__ s2, unsigned short* __restrict__ dst) {
  const float* src = blockIdx.z == 0 ? s0 : (blockIdx.z == 1 ? s1 : s2);
  unsigned short* d = dst + (size_t)blockIdx.z * Hd * Hd;
  __shared__ float tile[32][33];
  int tx = threadIdx.x & 31, ty = threadIdx.x >> 5;
  int bx = blockIdx.x * 32, by = blockIdx.y * 32;
  #pragma unroll
  for (int i = 0; i < 4; ++i)
    tile[ty + i * 8][tx] = src[(size_t)(by + ty + i * 8) * Hd + bx + tx];
  __syncthreads();
  #pragma unroll
  for (int i = 0; i < 4; ++i)
    d[(size_t)(bx + ty + i * 8) * Hd + by + tx] = f2bf(tile[tx][ty + i * 8]);
}

// ---------------- folded bias: biasf[h] = bf[h] + sum_c Wf[h][c]*bo_cat[c] ----------------
__global__ void k_biasf(const float* __restrict__ Wf_, const float* __restrict__ bfb,
                        const float* __restrict__ bo0, const float* __restrict__ bo1,
                        const float* __restrict__ bo2, float* __restrict__ biasf) {
  int h = blockIdx.x, t = threadIdx.x;
  float s = 0.f;
  for (int c = t; c < 3072; c += 256) {
    float b = c < 1024 ? bo0[c] : (c < 2048 ? bo1[c - 1024] : bo2[c - 2048]);
    s += Wf_[(size_t)h * 3072 + c] * b;
  }
  #pragma unroll
  for (int o = 32; o >= 1; o >>= 1) s += __shfl_xor(s, o);
  __shared__ float red[4];
  if ((t & 63) == 0) red[t >> 6] = s;
  __syncthreads();
  if (t == 0) biasf[h] = bfb[h] + red[0] + red[1] + red[2] + red[3];
}

// ---------------- pack per-layer small params ----------------
__global__ void k_setup(const float* A0, const float* A1, const float* A2,
                        const float* b0, const float* b1, const float* b2,
                        const float* D0, const float* D1, const float* D2,
                        const float* g0, const float* g1, const float* g2,
                        const float* e0, const float* e1, const float* e2,
                        float* Alog448, float* bg448,
                        float* D3, float* g3, float* be3) {
  int t = blockIdx.x * 256 + threadIdx.x;
  if (t < NT3) {
    int l = t < 64 ? 0 : (t < 192 ? 1 : 2);
    int o = t - (l == 0 ? 0 : (l == 1 ? 64 : 192));
    Alog448[t] = (l == 0 ? A0 : (l == 1 ? A1 : A2))[o];
    bg448[t]   = (l == 0 ? b0 : (l == 1 ? b1 : b2))[o];
  }
  if (t < 3072) {
    int l = t >> 10, o = t & 1023;
    D3[t]  = (l == 0 ? D0 : (l == 1 ? D1 : D2))[o];
    g3[t]  = (l == 0 ? g0 : (l == 1 ? g1 : g2))[o];
    be3[t] = (l == 0 ? e0 : (l == 1 ? e1 : e2))[o];
  }
}

// ---------------- embedding gather -> fp32 + bf16 ----------------
__global__ void k_embed(const int* __restrict__ x, const float* __restrict__ E,
                        float* __restrict__ emb, unsigned short* __restrict__ embbf) {
  int row = blockIdx.x, t = threadIdx.x;
  int id = x[row];
  f32x4 v = *(const f32x4*)(E + (size_t)id * Hd + t * 4);
  *(f32x4*)(emb + (size_t)row * Hd + t * 4) = v;
  us4 o;
  o[0] = f2bf(v[0]); o[1] = f2bf(v[1]); o[2] = f2bf(v[2]); o[3] = f2bf(v[3]);
  *(us4*)(embbf + (size_t)row * Hd + t * 4) = o;
}

// ---------------- bf16 NT GEMM, 2-phase double-buffered (proven r4) ----------------
template<int BM, int BN, int WM, int WN, int BF16_OUT>
__launch_bounds__(WM * WN * 64)
__global__ void gemm2ph(const unsigned short* __restrict__ A,
                        const unsigned short* __restrict__ Bw,
                        const float* __restrict__ bias,
                        void* __restrict__ Cv,
                        int N, int K, int lda, int ldb, int ldc, int coff, int tm)
{
  constexpr int NT = WM * WN * 64;
  constexpr int MF = BM / WM / 16;
  constexpr int NF = BN / WN / 16;
  constexpr int ASZ = BM * 64;
  constexpr int BSZ = BN * 64;
  constexpr int AR = (ASZ * 2) / (NT * 16);
  constexpr int BR = (BSZ * 2) / (NT * 16);
  __shared__ __align__(16) unsigned short Sm[2 * (ASZ + BSZ)];

  int T = gridDim.x;
  int orig = blockIdx.x;
  int q = T >> 3, r = T & 7;
  int xc = orig & 7, sdv = orig >> 3;
  int wgid = (xc < r ? xc * (q + 1) : r * (q + 1) + (xc - r) * q) + sdv;
  int n_t = wgid / tm, m_t = wgid % tm;
  int row0 = m_t * BM, col0 = n_t * BN;

  int tid = threadIdx.x;
  int wave = tid >> 6, lane = tid & 63;
  int wm = wave / WN, wn = wave % WN;
  int wr = wm * (BM / WM), wc = wn * (BN / WN);
  int lr = lane & 15;
  int klane = lane >> 4;

  f32x4 acc[MF][NF] = {};

  auto stage = [&](int buf, int k0) {
    unsigned short* Ab = Sm + buf * (ASZ + BSZ);
    unsigned short* Bb = Ab + ASZ;
    #pragma unroll
    for (int j = 0; j < AR; ++j) {
      int slot = j * NT + tid;
      int lrow = slot >> 3, c16 = slot & 7;
      int scol = (c16 ^ (lrow & 7)) * 8;
      gl_lds16(A + (size_t)(row0 + lrow) * lda + k0 + scol, Ab + (j * NT + wave * 64) * 8);
    }
    #pragma unroll
    for (int j = 0; j < BR; ++j) {
      int slot = j * NT + tid;
      int lrow = slot >> 3, c16 = slot & 7;
      int scol = (c16 ^ (lrow & 7)) * 8;
      int brow = col0 + lrow;
      if (brow >= N) brow = N - 1;
      gl_lds16(Bw + (size_t)brow * ldb + k0 + scol, Bb + (j * NT + wave * 64) * 8);
    }
  };

  auto compute = [&](int buf) {
    const unsigned short* Ab = Sm + buf * (ASZ + BSZ);
    const unsigned short* Bb = Ab + ASZ;
    #pragma unroll
    for (int kk = 0; kk < 2; ++kk) {
      short8 afr[MF], bfr[NF];
      #pragma unroll
      for (int m = 0; m < MF; ++m) {
        int row = wr + m * 16 + lr;
        int cs = (kk * 4 + klane) ^ (row & 7);
        afr[m] = *(const short8*)(Ab + row * 64 + cs * 8);
      }
      #pragma unroll
      for (int n = 0; n < NF; ++n) {
        int row = wc + n * 16 + lr;
        int cs = (kk * 4 + klane) ^ (row & 7);
        bfr[n] = *(const short8*)(Bb + row * 64 + cs * 8);
      }
      #pragma unroll
      for (int m = 0; m < MF; ++m)
        #pragma unroll
        for (int n = 0; n < NF; ++n)
          acc[m][n] = __builtin_amdgcn_mfma_f32_16x16x32_bf16(afr[m], bfr[n], acc[m][n], 0, 0, 0);
    }
  };

  int nt = K >> 6;
  stage(0, 0);
  __syncthreads();
  for (int t = 0; t < nt - 1; ++t) {
    stage((t & 1) ^ 1, (t + 1) * 64);
    compute(t & 1);
    __syncthreads();
  }
  compute((nt - 1) & 1);

  int rb = (lane >> 4) * 4;
  #pragma unroll
  for (int m = 0; m < MF; ++m) {
    #pragma unroll
    for (int n = 0; n < NF; ++n) {
      int gcol = col0 + wc + n * 16 + lr;
      if (gcol >= N) continue;
      float bv = bias ? bias[gcol] : 0.f;
      #pragma unroll
      for (int j = 0; j < 4; ++j) {
        int grow = row0 + wr + m * 16 + rb + j;
        float val = acc[m][n][j] + bv;
        if (BF16_OUT)
          ((unsigned short*)Cv)[(size_t)grow * ldc + coff + gcol] = f2bf(val);
        else
          ((float*)Cv)[(size_t)grow * ldc + coff + gcol] = val;
      }
    }
  }
}

// ---------------- batched 3-layer Wc GEMM (768 blocks, one launch) ----------------
__launch_bounds__(256)
__global__ void gemm_wc3(const unsigned short* __restrict__ St,
                         const unsigned short* __restrict__ Wc,
                         float* __restrict__ Cv)
{
  constexpr int ASZ = 128 * 64, BSZ = 128 * 64;
  __shared__ __align__(16) unsigned short Sm[2 * (ASZ + BSZ)];
  int T = gridDim.x;
  int orig = blockIdx.x;
  int q = T >> 3, r = T & 7;
  int xc = orig & 7, sdv = orig >> 3;
  int wgid = (xc < r ? xc * (q + 1) : r * (q + 1) + (xc - r) * q) + sdv;
  int l = wgid % 3;
  int w2 = wgid / 3;
  int n_t = w2 >> 5, m_t = w2 & 31;
  const int owgl = l == 0 ? 0 : (l == 1 ? 64 : 192);
  const int K = 64 << l;
  const unsigned short* A = St + owgl;
  const unsigned short* Bw = Wc + (size_t)owgl * Hd;
  int row0 = m_t * 128, col0 = n_t * 128;

  int tid = threadIdx.x;
  int wave = tid >> 6, lane = tid & 63;
  int wm = wave >> 1, wn = wave & 1;
  int wr = wm * 64, wc = wn * 64;
  int lr = lane & 15, klane = lane >> 4;

  f32x4 acc[4][4] = {};
  auto stage = [&](int buf, int k0) {
    unsigned short* Ab = Sm + buf * (ASZ + BSZ);
    unsigned short* Bb = Ab + ASZ;
    #pragma unroll
    for (int j = 0; j < 4; ++j) {
      int slot = j * 256 + tid;
      int lrow = slot >> 3, c16 = slot & 7;
      int scol = (c16 ^ (lrow & 7)) * 8;
      gl_lds16(A + (size_t)(row0 + lrow) * NT3 + k0 + scol, Ab + (j * 256 + wave * 64) * 8);
      gl_lds16(Bw + (size_t)(col0 + lrow) * K + k0 + scol, Bb + (j * 256 + wave * 64) * 8);
    }
  };
  auto compute = [&](int buf) {
    const unsigned short* Ab = Sm + buf * (ASZ + BSZ);
    const unsigned short* Bb = Ab + ASZ;
    #pragma unroll
    for (int kk = 0; kk < 2; ++kk) {
      short8 afr[4], bfr[4];
      #pragma unroll
      for (int m = 0; m < 4; ++m) {
        int row = wr + m * 16 + lr;
        int cs = (kk * 4 + klane) ^ (row & 7);
        afr[m] = *(const short8*)(Ab + row * 64 + cs * 8);
      }
      #pragma unroll
      for (int n = 0; n < 4; ++n) {
        int row = wc + n * 16 + lr;
        int cs = (kk * 4 + klane) ^ (row & 7);
        bfr[n] = *(const short8*)(Bb + row * 64 + cs * 8);
      }
      #pragma unroll
      for (int m = 0; m < 4; ++m)
        #pragma unroll
        for (int n = 0; n < 4; ++n)
          acc[m][n] = __builtin_amdgcn_mfma_f32_16x16x32_bf16(afr[m], bfr[n], acc[m][n], 0, 0, 0);
    }
  };
  int nt = K >> 6;
  stage(0, 0);
  __syncthreads();
  for (int t = 0; t < nt - 1; ++t) {
    stage((t & 1) ^ 1, (t + 1) * 64);
    compute(t & 1);
    __syncthreads();
  }
  compute((nt - 1) & 1);

  int rb = (lane >> 4) * 4;
  #pragma unroll
  for (int m = 0; m < 4; ++m)
    #pragma unroll
    for (int n = 0; n < 4; ++n) {
      int gcol = l * Hd + col0 + wc + n * 16 + lr;
      #pragma unroll
      for (int j = 0; j < 4; ++j) {
        int grow = row0 + wr + m * 16 + rb + j;
        Cv[(size_t)grow * 3072 + gcol] = acc[m][n][j];
      }
    }
}

// ---------------- block-diagonal composed-weight GEMM (one launch, 3 layers) ----------------
__launch_bounds__(256)
__global__ void gemm_bd3(const unsigned short* __restrict__ Awf,
                         const unsigned short* __restrict__ Bwo,
                         unsigned short* __restrict__ Cw)
{
  constexpr int ASZ = 128 * 64, BSZ = 128 * 64;
  __shared__ __align__(16) unsigned short Sm[2 * (ASZ + BSZ)];
  int T = gridDim.x;
  int orig = blockIdx.x;
  int q = T >> 3, r = T & 7;
  int xc = orig & 7, sdv = orig >> 3;
  int wgid = (xc < r ? xc * (q + 1) : r * (q + 1) + (xc - r) * q) + sdv;
  int n_g = wgid / 8, m_t = wgid % 8;
  int li = n_g >> 3, n_t = n_g & 7;
  const unsigned short* A = Awf + li * Hd;
  const unsigned short* Bw = Bwo + ((size_t)li << 20);
  int row0 = m_t * 128, col0 = n_t * 128;

  int tid = threadIdx.x;
  int wave = tid >> 6, lane = tid & 63;
  int wm = wave >> 1, wn = wave & 1;
  int wr = wm * 64, wc = wn * 64;
  int lr = lane & 15, klane = lane >> 4;

  f32x4 acc[4][4] = {};
  auto stage = [&](int buf, int k0) {
    unsigned short* Ab = Sm + buf * (ASZ + BSZ);
    unsigned short* Bb = Ab + ASZ;
    #pragma unroll
    for (int j = 0; j < 4; ++j) {
      int slot = j * 256 + tid;
      int lrow = slot >> 3, c16 = slot & 7;
      int scol = (c16 ^ (lrow & 7)) * 8;
      gl_lds16(A + (size_t)(row0 + lrow) * 3072 + k0 + scol, Ab + (j * 256 + wave * 64) * 8);
      gl_lds16(Bw + (size_t)(col0 + lrow) * 1024 + k0 + scol, Bb + (j * 256 + wave * 64) * 8);
    }
  };
  auto compute = [&](int buf) {
    const unsigned short* Ab = Sm + buf * (ASZ + BSZ);
    const unsigned short* Bb = Ab + ASZ;
    #pragma unroll
    for (int kk = 0; kk < 2; ++kk) {
      short8 afr[4], bfr[4];
      #pragma unroll
      for (int m = 0; m < 4; ++m) {
        int row = wr + m * 16 + lr;
        int cs = (kk * 4 + klane) ^ (row & 7);
        afr[m] = *(const short8*)(Ab + row * 64 + cs * 8);
      }
      #pragma unroll
      for (int n = 0; n < 4; ++n) {
        int row = wc + n * 16 + lr;
        int cs = (kk * 4 + klane) ^ (row & 7);
        bfr[n] = *(const short8*)(Bb + row * 64 + cs * 8);
      }
      #pragma unroll
      for (int m = 0; m < 4; ++m)
        #pragma unroll
        for (int n = 0; n < 4; ++n)
          acc[m][n] = __builtin_amdgcn_mfma_f32_16x16x32_bf16(afr[m], bfr[n], acc[m][n], 0, 0, 0);
    }
  };
  stage(0, 0);
  __syncthreads();
  for (int t = 0; t < 15; ++t) {
    stage((t & 1) ^ 1, (t + 1) * 64);
    compute(t & 1);
    __syncthreads();
  }
  compute(1);

  int rb = (lane >> 4) * 4;
  #pragma unroll
  for (int m = 0; m < 4; ++m)
    #pragma unroll
    for (int n = 0; n < 4; ++n) {
      int gcol = li * Hd + col0 + wc + n * 16 + lr;
      #pragma unroll
      for (int j = 0; j < 4; ++j) {
        int grow = row0 + wr + m * 16 + rb + j;
        Cw[(size_t)grow * 3072 + gcol] = f2bf(acc[m][n][j]);
      }
    }
}

// ---------------- 8-phase 256x256 NT GEMM (logits) — ONE barrier per phase ----------------
// r14 change: drop the pre-MFMA barrier; per phase: reads -> stage -> MFMA ->
// [vmcnt at ph4/ph8] -> s_barrier. Ledger: barrier-per-phase bounds wave skew
// to ONE phase window; all intra-phase (read-region, stage-region) pairs are
// DISJOINT (ph1: reads buf0.h0A+buf0.B, stages buf1.h1; ph3: reads buf0.Ah1,
// stages buf0.Ah0; ph4: +buf0.Bh0; ph5: reads buf1, stages buf0.h1; ph7/8:
// reads buf1.Ah1, stages buf1.h0); every stage target's last reader closed
// >=1 barrier earlier. vmcnt(4) BEFORE the collective barrier makes staging
// completion collective (per-wave FIFO leaves only this-iter ph3+ph4 / ph7+ph8
// in flight). Waves now skew within a phase -> LDS-read pipe overlaps other
// waves' MFMA drain (the two pipes were ~50/50 serialized before).
__launch_bounds__(512)
__global__ void gemm8ph(const unsigned short* __restrict__ A,
                        const unsigned short* __restrict__ Bw,
                        const float* __restrict__ bias,
                        float* __restrict__ Cv,
                        int N, int K, int lda, int ldb, int ldc, int tn)
{
  __shared__ __align__(16) unsigned short Sm[65536];  // A: 4x8192, B: 4x8192 (128 KB)

  int wgid = blockIdx.x;
  int grp = wgid >> 8;
  int rem = wgid & 255;
  int n_t = grp * 16 + (rem >> 4);
  int m_t = rem & 15;
  int row0 = m_t * 256, col0 = n_t * 256;

  int tid = threadIdx.x;
  int wave = tid >> 6, lane = tid & 63;
  int wm = wave >> 2, wn = wave & 3;   // 2M x 4N
  int lr = lane & 15, klane = lane >> 4;

  f32x4 acc[8][4] = {};

  auto stageA = [&](int b, int h, int kt) {
    unsigned short* base = Sm + (b * 2 + h) * 8192;
    #pragma unroll
    for (int j = 0; j < 2; ++j) {
      int slot = j * 512 + tid;
      int lrow = slot >> 3, c16 = slot & 7;
      int scol = (c16 ^ (lrow & 7)) * 8;
      gl_lds16(A + (size_t)(row0 + h * 128 + lrow) * lda + kt * 64 + scol,
               base + (j * 512 + wave * 64) * 8);
    }
  };
  auto stageB = [&](int b, int h, int kt) {
    unsigned short* base = Sm + 32768 + (b * 2 + h) * 8192;
    #pragma unroll
    for (int j = 0; j < 2; ++j) {
      int slot = j * 512 + tid;
      int lrow = slot >> 3, c16 = slot & 7;
      int scol = (c16 ^ (lrow & 7)) * 8;
      gl_lds16(Bw + (size_t)(col0 + h * 128 + lrow) * ldb + kt * 64 + scol,
               base + (j * 512 + wave * 64) * 8);
    }
  };
  auto readA = [&](short8* afr, int b, int mh, int kk) {
    const unsigned short* base = Sm + (b * 2 + mh) * 8192;
    #pragma unroll
    for (int f = 0; f < 4; ++f) {
      int rowin = f * 32 + wm * 16 + lr;
      int cs = (kk * 4 + klane) ^ (rowin & 7);
      afr[f] = *(const short8*)(base + rowin * 64 + cs * 8);
    }
  };
  auto readB = [&](short8* bfr, int b, int kk) {
    #pragma unroll
    for (int n = 0; n < 4; ++n) {
      int rowin = (n & 1) * 64 + wn * 16 + lr;
      const unsigned short* base = Sm + 32768 + (b * 2 + (n >> 1)) * 8192;
      int cs = (kk * 4 + klane) ^ (rowin & 7);
      bfr[n] = *(const short8*)(base + rowin * 64 + cs * 8);
    }
  };

  #define MFMA16(mh, afr, bfr)                                                  \
    __builtin_amdgcn_s_setprio(1);                                              \
    _Pragma("unroll")                                                           \
    for (int f = 0; f < 4; ++f)                                                 \
      _Pragma("unroll")                                                         \
      for (int n = 0; n < 4; ++n)                                               \
        acc[(mh) * 4 + f][n] = __builtin_amdgcn_mfma_f32_16x16x32_bf16(         \
            afr[f], bfr[n], acc[(mh) * 4 + f][n], 0, 0, 0);                     \
    __builtin_amdgcn_s_setprio(0);

  #define BAR()   __builtin_amdgcn_s_barrier()
  #define VM4()   asm volatile("s_waitcnt vmcnt(4)" ::: "memory")
  #define VM0()   asm volatile("s_waitcnt vmcnt(0)" ::: "memory")

  int nt = K >> 6;          // 16
  int iters = K >> 7;       // 8

  // prologue: T0 all 4 halves + T1.Ah0, T1.Bh0
  stageA(0, 0, 0); stageB(0, 0, 0); stageB(0, 1, 0); stageA(0, 1, 0);
  stageA(1, 0, 1); stageB(1, 0, 1);
  VM4(); BAR();

  short8 afr[4], bfr0[4], bfr1[4];
  for (int i = 0; i < iters; ++i) {
    int t1 = 2 * i + 1, t2 = 2 * i + 2, t3 = 2 * i + 3;
    bool last = (i == iters - 1);
    // ph1: reads buf0.h0A + buf0.B | stage buf1.Bh1,Ah1 <- T1
    readA(afr, 0, 0, 0); readB(bfr0, 0, 0);
    stageB(1, 1, t1); stageA(1, 1, t1);
    MFMA16(0, afr, bfr0);
    BAR();
    // ph2
    readA(afr, 0, 0, 1); readB(bfr1, 0, 1);
    MFMA16(0, afr, bfr1);
    BAR();
    // ph3: reads buf0.Ah1 | stage buf0.Ah0 <- T2
    readA(afr, 0, 1, 0);
    if (t2 < nt) stageA(0, 0, t2);
    MFMA16(1, afr, bfr0);
    BAR();
    // ph4: stage buf0.Bh0 <- T2 | vmcnt
    readA(afr, 0, 1, 1);
    if (t2 < nt) stageB(0, 0, t2);
    MFMA16(1, afr, bfr1);
    if (last) { VM0(); } else { VM4(); }
    BAR();
    // ph5: reads buf1 | stage buf0.Bh1,Ah1 <- T2
    readA(afr, 1, 0, 0); readB(bfr0, 1, 0);
    if (t2 < nt) { stageB(0, 1, t2); stageA(0, 1, t2); }
    MFMA16(0, afr, bfr0);
    BAR();
    // ph6
    readA(afr, 1, 0, 1); readB(bfr1, 1, 1);
    MFMA16(0, afr, bfr1);
    BAR();
    // ph7: stage buf1.Ah0 <- T3
    readA(afr, 1, 1, 0);
    if (t3 < nt) stageA(1, 0, t3);
    MFMA16(1, afr, bfr0);
    BAR();
    // ph8: stage buf1.Bh0 <- T3 | vmcnt
    readA(afr, 1, 1, 1);
    if (t3 < nt) stageB(1, 0, t3);
    MFMA16(1, afr, bfr1);
    if (!last) { VM4(); }
    BAR();
  }

  int rb = (lane >> 4) * 4;
  #pragma unroll
  for (int idx = 0; idx < 8; ++idx) {
    int mh = idx >> 2, f = idx & 3;
    int growb = row0 + mh * 128 + f * 32 + wm * 16 + rb;
    #pragma unroll
    for (int n = 0; n < 4; ++n) {
      int gcol = col0 + (n & 1) * 64 + (n >> 1) * 128 + wn * 16 + lr;
      float bv = bias[gcol];
      #pragma unroll
      for (int j = 0; j < 4; ++j)
        Cv[(size_t)(growb + j) * ldc + gcol] = acc[idx][n][j] + bv;
    }
  }
  #undef MFMA16
  #undef BAR
  #undef VM4
  #undef VM0
}

// ---------------- packed 3-layer chunked diagonal scan ----------------
__global__ void k_scanA(const float* __restrict__ gzbx, const float* __restrict__ Alog448,
                        const float* __restrict__ bg448,
                        float* __restrict__ st, float* __restrict__ carry) {
  int gid = blockIdx.x * 256 + threadIdx.x;
  if (gid >= Bdim * NCH * NT3) return;
  int n = gid % NT3;
  int c = (gid / NT3) % NCH;
  int b = gid / (NT3 * NCH);
  float a = expf(Alog448[n]);
  float bgv = bg448[n];
  float s = 0.f;
  size_t rbase = (size_t)b * Sd + (size_t)c * CH;
  for (int t = 0; t < CH; ++t) {
    size_t row = rbase + t;
    float gzv = gzbx[row * 896 + n];
    float bxv = gzbx[row * 896 + 448 + n];
    float gv = 1.f / (1.f + expf(-(gzv + bgv)));
    s = a * s + gv * bxv;
    st[row * NT3 + n] = s;
  }
  carry[((size_t)b * NCH + c) * NT3 + n] = s;
}

__global__ void k_scanB(const float* __restrict__ carry, const float* __restrict__ Alog448,
                        float* __restrict__ cin) {
  int i = blockIdx.x * 256 + threadIdx.x;
  if (i >= Bdim * NT3) return;
  int b = i / NT3, n = i % NT3;
  float aC = expf((float)CH * Alog448[n]);
  float s = 0.f;
  for (int c = 0; c < NCH; ++c) {
    cin[((size_t)b * NCH + c) * NT3 + n] = s;
    s = aC * s + carry[((size_t)b * NCH + c) * NT3 + n];
  }
}

__global__ void k_scanC(const float* __restrict__ st, const float* __restrict__ cin,
                        const float* __restrict__ Alog448, unsigned short* __restrict__ stbf) {
  size_t gid = (size_t)blockIdx.x * 256 + threadIdx.x;
  if (gid >= (size_t)BSd * NT3) return;
  int n = gid % NT3;
  int row = gid / NT3;
  int b = row / Sd, sg = row % Sd;
  int c = sg / CH, t = sg % CH;
  float cv = cin[((size_t)b * NCH + c) * NT3 + n];
  float val = st[gid] + expf((float)(t + 1) * Alog448[n]) * cv;
  stbf[gid] = f2bf(val);
}

// ---------------- 3-layer fused LN ----------------
__global__ void k_ln3(const float* __restrict__ y3, const float* __restrict__ emb,
                      const float* __restrict__ D3, const float* __restrict__ g3,
                      const float* __restrict__ be3, unsigned short* __restrict__ z3) {
  int row = blockIdx.x, ly = blockIdx.y, t = threadIdx.x;
  const float* y = y3 + (size_t)row * 3072 + ly * 1024;
  f32x4 yv = *(const f32x4*)(y + t * 4);
  f32x4 ev = *(const f32x4*)(emb + (size_t)row * Hd + t * 4);
  float vals[4];
  float sum = 0.f, sq = 0.f;
  #pragma unroll
  for (int j = 0; j < 4; ++j) {
    float coef = D3[ly * 1024 + t * 4 + j] + 1.f;
    float v = yv[j] + coef * ev[j];
    vals[j] = v; sum += v; sq += v * v;
  }
  #pragma unroll
  for (int o = 32; o >= 1; o >>= 1) {
    sum += __shfl_xor(sum, o);
    sq += __shfl_xor(sq, o);
  }
  __shared__ float red[2][4];
  int w = t >> 6, lane = t & 63;
  if (lane == 0) { red[0][w] = sum; red[1][w] = sq; }
  __syncthreads();
  sum = red[0][0] + red[0][1] + red[0][2] + red[0][3];
  sq  = red[1][0] + red[1][1] + red[1][2] + red[1][3];
  float mean = sum * (1.f / Hd);
  float var = sq * (1.f / Hd) - mean * mean;
  float rs = rsqrtf(var + EPSf);
  us4 o4;
  #pragma unroll
  for (int j = 0; j < 4; ++j) {
    float z = (vals[j] - mean) * rs * g3[ly * 1024 + t * 4 + j] + be3[ly * 1024 + t * 4 + j];
    o4[j] = f2bf(z);
  }
  *(us4*)(z3 + (size_t)row * 3072 + ly * 1024 + t * 4) = o4;
}

// ---------------- final LN (coef 1) ----------------
__global__ void k_ln(const float* __restrict__ y, const float* __restrict__ emb,
                     const float* __restrict__ g, const float* __restrict__ be,
                     unsigned short* __restrict__ out) {
  int row = blockIdx.x, t = threadIdx.x;
  f32x4 yv = *(const f32x4*)(y + (size_t)row * Hd + t * 4);
  f32x4 ev = *(const f32x4*)(emb + (size_t)row * Hd + t * 4);
  float vals[4];
  float sum = 0.f, sq = 0.f;
  #pragma unroll
  for (int j = 0; j < 4; ++j) {
    float v = yv[j] + ev[j];
    vals[j] = v; sum += v; sq += v * v;
  }
  #pragma unroll
  for (int o = 32; o >= 1; o >>= 1) {
    sum += __shfl_xor(sum, o);
    sq += __shfl_xor(sq, o);
  }
  __shared__ float red[2][4];
  int w = t >> 6, lane = t & 63;
  if (lane == 0) { red[0][w] = sum; red[1][w] = sq; }
  __syncthreads();
  sum = red[0][0] + red[0][1] + red[0][2] + red[0][3];
  sq  = red[1][0] + red[1][1] + red[1][2] + red[1][3];
  float mean = sum * (1.f / Hd);
  float var = sq * (1.f / Hd) - mean * mean;
  float rs = rsqrtf(var + EPSf);
  us4 o4;
  #pragma unroll
  for (int j = 0; j < 4; ++j) {
    float z = (vals[j] - mean) * rs * g[t * 4 + j] + be[t * 4 + j];
    o4[j] = f2bf(z);
  }
  *(us4*)(out + (size_t)row * Hd + t * 4) = o4;
}

extern "C" void kernel_launch(void* const* d_in, const int* in_sizes, int n_in,
                              void* d_out, int out_size, void* d_ws, size_t ws_size,
                              hipStream_t stream) {
  (void)in_sizes; (void)n_in; (void)out_size; (void)ws_size;
  const int* x = (const int*)d_in[0];
  const float* E = (const float*)d_in[1];
  const float* Wf_ = (const float*)d_in[32];
  const float* bfb = (const float*)d_in[33];
  const float* gfp = (const float*)d_in[34];
  const float* bef = (const float*)d_in[35];
  const float* Wh_ = (const float*)d_in[36];
  const float* bh = (const float*)d_in[37];

  char* wsb = (char*)d_ws;
  size_t off = 0;
  auto alloc = [&](size_t bytes) -> void* {
    void* p = wsb + off;
    off += (bytes + 255) & ~(size_t)255;
    return p;
  };
  float* emb             = (float*)alloc((size_t)BSd * Hd * 4);
  unsigned short* embbf  = (unsigned short*)alloc((size_t)BSd * Hd * 2);
  unsigned short* wgwbbf = (unsigned short*)alloc((size_t)896 * Hd * 2);
  unsigned short* wcbf   = (unsigned short*)alloc((size_t)NT3 * Hd * 2);
  unsigned short* wotbf  = (unsigned short*)alloc((size_t)3 * Hd * Hd * 2);
  unsigned short* wfbf   = (unsigned short*)alloc((size_t)3 * Hd * Hd * 2);
  unsigned short* wcombbf= (unsigned short*)alloc((size_t)Hd * 3 * Hd * 2);
  unsigned short* whbf   = (unsigned short*)alloc((size_t)Vd * Hd * 2);
  float* gzbx            = (float*)alloc((size_t)BSd * 896 * 4);
  float* stl             = (float*)alloc((size_t)BSd * NT3 * 4);
  unsigned short* stbf   = (unsigned short*)alloc((size_t)BSd * NT3 * 2);
  float* carry           = (float*)alloc((size_t)Bdim * NCH * NT3 * 4);
  float* cin             = (float*)alloc((size_t)Bdim * NCH * NT3 * 4);
  float* ybuf3           = (float*)alloc((size_t)BSd * 3072 * 4);
  unsigned short* zbf3   = (unsigned short*)alloc((size_t)BSd * 3072 * 2);
  unsigned short* zbf    = (unsigned short*)alloc((size_t)BSd * Hd * 2);
  float* Alog448         = (float*)alloc(NT3 * 4);
  float* bg448           = (float*)alloc(NT3 * 4);
  float* D3              = (float*)alloc(3072 * 4);
  float* g3              = (float*)alloc(3072 * 4);
  float* be3             = (float*)alloc(3072 * 4);
  float* biasf           = (float*)alloc(Hd * 4);

  k_embed<<<BSd, 256, 0, stream>>>(x, E, emb, embbf);

  // batched weight conversion (Wg, Wb, Wc, Wf, Wh)
  {
    CvtTab tab;
    const int rowoff_g[3] = {0, 64, 192};
    int j = 0;
    int n4s[11];
    for (int i = 0; i < 3; ++i) { tab.src[j] = (const float*)d_in[2 + 10 * i + 4]; tab.dst[j] = wgwbbf + (size_t)rowoff_g[i] * Hd;         n4s[j] = (64 << i) * Hd / 4; ++j; }
    for (int i = 0; i < 3; ++i) { tab.src[j] = (const float*)d_in[2 + 10 * i + 1]; tab.dst[j] = wgwbbf + (size_t)(448 + rowoff_g[i]) * Hd;  n4s[j] = (64 << i) * Hd / 4; ++j; }
    for (int i = 0; i < 3; ++i) { tab.src[j] = (const float*)d_in[2 + 10 * i + 2]; tab.dst[j] = wcbf + (size_t)rowoff_g[i] * Hd;            n4s[j] = (64 << i) * Hd / 4; ++j; }
    tab.src[j] = Wf_; tab.dst[j] = wfbf; n4s[j] = 3 * Hd * Hd / 4; ++j;
    tab.src[j] = Wh_; tab.dst[j] = whbf; n4s[j] = Vd * Hd / 4; ++j;
    tab.start[0] = 0;
    for (int k = 0; k < 11; ++k) tab.start[k + 1] = tab.start[k] + (n4s[k] + 255) / 256;
    k_cvt_all<<<tab.start[11], 256, 0, stream>>>(tab);
  }

  // Wo transposed-convert (for composed-weight GEMMs)
  k_cvtT<<<dim3(32, 32, 3), 256, 0, stream>>>(
      (const float*)d_in[8], (const float*)d_in[18], (const float*)d_in[28], wotbf);

  k_setup<<<12, 256, 0, stream>>>(
      (const float*)d_in[2], (const float*)d_in[12], (const float*)d_in[22],
      (const float*)d_in[7], (const float*)d_in[17], (const float*)d_in[27],
      (const float*)d_in[5], (const float*)d_in[15], (const float*)d_in[25],
      (const float*)d_in[10], (const float*)d_in[20], (const float*)d_in[30],
      (const float*)d_in[11], (const float*)d_in[21], (const float*)d_in[31],
      Alog448, bg448, D3, g3, be3);

  k_biasf<<<Hd, 256, 0, stream>>>(Wf_, bfb,
      (const float*)d_in[9], (const float*)d_in[19], (const float*)d_in[29], biasf);

  // composed weights in ONE block-diagonal launch (192 blocks)
  gemm_bd3<<<192, 256, 0, stream>>>(wfbf, wotbf, wcombbf);

  const int TM = BSd / 128;  // 32

  // merged gate+Bx GEMM: [BSd,1024] x [896,1024]^T -> gzbx [BSd,896]
  gemm2ph<128,128,2,2,0><<<(896 / 128) * TM, 256, 0, stream>>>(
      embbf, wgwbbf, nullptr, gzbx, 896, Hd, Hd, Hd, 896, 0, TM);

  // packed 3-layer scan
  {
    int totA = Bdim * NCH * NT3;
    k_scanA<<<(totA + 255) / 256, 256, 0, stream>>>(gzbx, Alog448, bg448, stl, carry);
    k_scanB<<<(Bdim * NT3 + 255) / 256, 256, 0, stream>>>(carry, Alog448, cin);
    size_t totC = (size_t)BSd * NT3;
    k_scanC<<<(int)((totC + 255) / 256), 256, 0, stream>>>(stl, cin, Alog448, stbf);
  }

  // all 3 Wc GEMMs in ONE launch (768 blocks, layer interleaved)
  gemm_wc3<<<768, 256, 0, stream>>>(stbf, wcbf, ybuf3);

  // one 3-layer LN
  k_ln3<<<dim3(BSd, 3), 256, 0, stream>>>(ybuf3, emb, D3, g3, be3, zbf3);

  // fused = z3 @ Wcomb^T + biasf  (replaces 3 Wo GEMMs + Wf GEMM)
  gemm2ph<128,128,2,2,0><<<(Hd / 128) * TM, 256, 0, stream>>>(
      zbf3, wcombbf, biasf, ybuf3, Hd, 3 * Hd, 3 * Hd, 3 * Hd, Hd, 0, TM);
  k_ln<<<BSd, 256, 0, stream>>>(ybuf3, emb, gfp, bef, zbf);

  // logits: 8-phase 256x256, supertile dispatch, ONE barrier per phase
  const int TN = Vd / 256;  // 125
  gemm8ph<<<(BSd / 256) * TN, 512, 0, stream>>>(
      zbf, whbf, bh, (float*)d_out, Vd, Hd, Hd, Hd, Vd, TN);
}